// Round 1
// baseline (842.514 us; speedup 1.0000x reference)
//
#include <hip/hip_runtime.h>
#include <hip/hip_fp16.h>

#define MEM  1024
#define B_   128
#define L_   512
#define M_   (B_*L_)      // 65536 rows
#define N_   (2*MEM)      // 2048 cols
#define K_   512

#define SCALE_U 16.0f
#define SCALE_W 1024.0f
#define INV_SCALE (1.0f / (16.0f * 1024.0f))

typedef __attribute__((ext_vector_type(8))) _Float16 half8;
typedef __attribute__((ext_vector_type(4))) float f32x4;

__device__ __forceinline__ float fast_tanh(float x) {
    float e = __expf(2.0f * x);
    return 1.0f - 2.0f / (e + 1.0f);
}
__device__ __forceinline__ float fast_sigmoid(float x) {
    return 1.0f / (1.0f + __expf(-x));
}
__device__ __forceinline__ void gl_lds16(const void* g, void* l) {
    __builtin_amdgcn_global_load_lds(
        (const __attribute__((address_space(1))) void*)g,
        (__attribute__((address_space(3))) void*)l, 16, 0, 0);
}

// fp32 -> scaled (hi fp16 RNE, lo fp16 = RNE(x*s - hi)); unbiased 2-way split.
__global__ void split_fp32_fp16x2(const float* __restrict__ in,
                                  unsigned short* __restrict__ hi,
                                  unsigned short* __restrict__ lo,
                                  int n4, float scale) {
    int i = blockIdx.x * 256 + threadIdx.x;
    if (i >= n4) return;
    const float4 v = reinterpret_cast<const float4*>(in)[i];
    float vs[4] = {v.x, v.y, v.z, v.w};
    unsigned short hs_[4], ls_[4];
#pragma unroll
    for (int c = 0; c < 4; ++c) {
        float xs = vs[c] * scale;
        __half h = __float2half_rn(xs);
        float r = xs - __half2float(h);
        __half l = __float2half_rn(r);
        hs_[c] = __half_as_ushort(h);
        ls_[c] = __half_as_ushort(l);
    }
    ushort4 h4, l4;
    h4.x = hs_[0]; h4.y = hs_[1]; h4.z = hs_[2]; h4.w = hs_[3];
    l4.x = ls_[0]; l4.y = ls_[1]; l4.z = ls_[2]; l4.w = ls_[3];
    reinterpret_cast<ushort4*>(hi)[i] = h4;
    reinterpret_cast<ushort4*>(lo)[i] = l4;
}

// Paired-half GEMM, fp32-A staged directly (split to fp16 hi/lo in VALU).
// R5: 2-phase double-buffered pipeline (T3-min + T5):
//   BM=256 (x2 col-halves of 128), BK=32, 512 threads (8 waves: 4 wm x 2 wn),
//   128 KB LDS (2 buffers), raw s_barrier + overlapped s_waitcnt vmcnt(0);
//   global-load latency hides under the previous phase's 96 MFMAs.
// Swizzles unchanged from the verified R3/R4 kernel:
//   A: 16B chunks slot-swizzled slot = chunk ^ (row&7) (global-source side)
//   B: fp16, q2 XOR swizzle
#define TM 256
#define TN 128
#define BK 32
__global__ __launch_bounds__(512, 2) void gemm_paired_kernel(
    const float* __restrict__ u,
    const unsigned short* __restrict__ wh, const unsigned short* __restrict__ wl,
    const float* __restrict__ bias,
    float* __restrict__ z_out) {   // M_ x MEM
    __shared__ __attribute__((aligned(16))) float Af[2][TM * BK];            // 2 x 32 KB
    __shared__ __attribute__((aligned(16))) unsigned short Bh0[2][TN * BK];  // 2 x 8 KB
    __shared__ __attribute__((aligned(16))) unsigned short Bl0[2][TN * BK];
    __shared__ __attribute__((aligned(16))) unsigned short Bh1[2][TN * BK];
    __shared__ __attribute__((aligned(16))) unsigned short Bl1[2][TN * BK];

    const int tid = threadIdx.x;
    // supertile: group of 64 blocks = 8 M-tiles (fast) x 8 N-tiles
    const int id  = blockIdx.x;                  // 0..2047
    const int mt  = (id >> 6) * 8 + (id & 7);    // 0..255
    const int nt  = (id >> 3) & 7;               // 0..7
    const int tileM = mt * TM;
    const int tileN = nt * TN;

    const int lane = tid & 63, w = tid >> 6;
    const int wm = w & 3, wn = w >> 2;           // 4 M-chunks x 2 N-chunks of 64
    const int lrow = lane & 15, quad = lane >> 4;
    const int q2 = quad ^ ((lrow >> 1) & 3);     // B bank-conflict XOR swizzle

    f32x4 acc0[4][4] = {};
    f32x4 acc1[4][4] = {};

    // A staging: 4 calls of 512 lanes x 16B cover 256x32 floats.
    size_t aoff[4];
#pragma unroll
    for (int c = 0; c < 4; ++c) {
        const int p = c * 512 + tid;          // LDS chunk index
        const int row = p >> 3;
        const int chunk = (p & 7) ^ (row & 7);
        aoff[c] = (size_t)(tileM + row) * K_ + chunk * 4;
    }
    // B staging: 1 chunk (16B = 8 shorts) per array per thread, q2-swizzled source.
    const int rB = tid >> 2;                       // 0..127
    const int gsB = (tid & 3) ^ ((rB >> 1) & 3);
    const size_t sB0 = (size_t)(tileN + rB) * K_ + gsB * 8;
    const size_t sB1 = (size_t)(tileN + 1024 + rB) * K_ + gsB * 8;

#define STAGE(BUF, KT) do {                                               \
        const size_t ko_ = (size_t)(KT) * BK;                             \
        _Pragma("unroll")                                                 \
        for (int c = 0; c < 4; ++c)                                       \
            gl_lds16(u + aoff[c] + ko_, &Af[BUF][(c * 512 + tid) * 4]);   \
        gl_lds16(wh + sB0 + ko_, &Bh0[BUF][tid * 8]);                     \
        gl_lds16(wl + sB0 + ko_, &Bl0[BUF][tid * 8]);                     \
        gl_lds16(wh + sB1 + ko_, &Bh1[BUF][tid * 8]);                     \
        gl_lds16(wl + sB1 + ko_, &Bl1[BUF][tid * 8]);                     \
    } while (0)

#define COMPUTE(BUF) do {                                                            \
        half8 ahf[4], alf[4];                                                        \
        _Pragma("unroll")                                                            \
        for (int i = 0; i < 4; ++i) {                                                \
            const int r = wm * 64 + i * 16 + lrow;                                   \
            const int sw = r & 7;                                                    \
            const f32x4 t0 = *(const f32x4*)&Af[BUF][(r * 8 + ((quad * 2)     ^ sw)) * 4]; \
            const f32x4 t1 = *(const f32x4*)&Af[BUF][(r * 8 + ((quad * 2 + 1) ^ sw)) * 4]; \
            half8 h, l;                                                              \
            _Pragma("unroll")                                                        \
            for (int e = 0; e < 4; ++e) {                                            \
                float xs = t0[e] * SCALE_U;                                          \
                _Float16 hh = (_Float16)xs;                                          \
                h[e] = hh;                                                           \
                l[e] = (_Float16)(xs - (float)hh);                                   \
                xs = t1[e] * SCALE_U;                                                \
                hh = (_Float16)xs;                                                   \
                h[e + 4] = hh;                                                       \
                l[e + 4] = (_Float16)(xs - (float)hh);                               \
            }                                                                        \
            ahf[i] = h; alf[i] = l;                                                  \
        }                                                                            \
        __builtin_amdgcn_s_setprio(1);                                               \
        _Pragma("unroll")                                                            \
        for (int j = 0; j < 4; ++j) {                                                \
            const int bo = ((wn * 64 + j * 16 + lrow) * 4 + q2) * 8;                 \
            const half8 b0h = *(const half8*)&Bh0[BUF][bo];                          \
            const half8 b0l = *(const half8*)&Bl0[BUF][bo];                          \
            const half8 b1h = *(const half8*)&Bh1[BUF][bo];                          \
            const half8 b1l = *(const half8*)&Bl1[BUF][bo];                          \
            _Pragma("unroll")                                                        \
            for (int i = 0; i < 4; ++i) {                                            \
                f32x4 c0 = acc0[i][j];                                               \
                c0 = __builtin_amdgcn_mfma_f32_16x16x32_f16(ahf[i], b0h, c0, 0, 0, 0); \
                c0 = __builtin_amdgcn_mfma_f32_16x16x32_f16(ahf[i], b0l, c0, 0, 0, 0); \
                c0 = __builtin_amdgcn_mfma_f32_16x16x32_f16(alf[i], b0h, c0, 0, 0, 0); \
                acc0[i][j] = c0;                                                     \
                f32x4 c1 = acc1[i][j];                                               \
                c1 = __builtin_amdgcn_mfma_f32_16x16x32_f16(ahf[i], b1h, c1, 0, 0, 0); \
                c1 = __builtin_amdgcn_mfma_f32_16x16x32_f16(ahf[i], b1l, c1, 0, 0, 0); \
                c1 = __builtin_amdgcn_mfma_f32_16x16x32_f16(alf[i], b1h, c1, 0, 0, 0); \
                acc1[i][j] = c1;                                                     \
            }                                                                        \
        }                                                                            \
        __builtin_amdgcn_s_setprio(0);                                               \
    } while (0)

    // Prologue: fill buffer 0, full drain once.
    STAGE(0, 0);
    asm volatile("s_waitcnt vmcnt(0)" ::: "memory");
    __builtin_amdgcn_s_barrier();

    // 2-phase main loop: stage(next) overlaps compute(cur); the vmcnt(0)
    // at phase end has had a full MFMA phase to complete -> near-zero stall.
#pragma unroll 1
    for (int kt = 0; kt < K_ / BK; kt += 2) {
        STAGE(1, kt + 1);                 // kt+1 <= 15 always valid
        COMPUTE(0);
        asm volatile("s_waitcnt vmcnt(0)" ::: "memory");
        __builtin_amdgcn_s_barrier();
        if (kt + 2 < K_ / BK) STAGE(0, kt + 2);
        COMPUTE(1);
        asm volatile("s_waitcnt vmcnt(0)" ::: "memory");
        __builtin_amdgcn_s_barrier();
    }

    // Epilogue: fused z = 5*tanh((c1+b1)/5) + (c2+b2).
#pragma unroll
    for (int j = 0; j < 4; ++j) {
        const int c = tileN + wn * 64 + j * 16 + lrow;
        const float b1v = bias[c];
        const float b2v = bias[c + 1024];
#pragma unroll
        for (int i = 0; i < 4; ++i) {
            const int rowb = tileM + wm * 64 + i * 16 + quad * 4;
#pragma unroll
            for (int r = 0; r < 4; ++r) {
                float v1 = acc0[i][j][r] * INV_SCALE + b1v;
                v1 = fast_tanh(v1 * 0.2f) * 5.0f;
                const float v2 = acc1[i][j][r] * INV_SCALE + b2v;
                z_out[(size_t)(rowb + r) * MEM + c] = v1 + v2;
            }
        }
    }
#undef STAGE
#undef COMPUTE
}

// One thread per (b, m) chain; 16-deep register prefetch (4 KB/wave in flight).
__global__ __launch_bounds__(256) void scan_kernel(
    const float* __restrict__ z,      // M_ x MEM fused io+sb
    float* __restrict__ h_t,          // out: hf sequence
    const float* __restrict__ h0,
    float* __restrict__ hf_last) {
    const int idx = blockIdx.x * 256 + threadIdx.x;   // 0 .. 131071
    const int b = idx >> 10, m = idx & (MEM - 1);
    float hf = h0[idx];
    float hs = h0[B_ * MEM + idx];
    const size_t base = (size_t)b * L_ * MEM + m;

    float zv[16], zn[16];
#pragma unroll
    for (int j = 0; j < 16; ++j) zv[j] = z[base + (size_t)j * MEM];

    for (int l0 = 0; l0 < L_; l0 += 16) {
        const bool more = (l0 + 16) < L_;
        if (more) {
#pragma unroll
            for (int j = 0; j < 16; ++j)
                zn[j] = z[base + (size_t)(l0 + 16 + j) * MEM];
        }
#pragma unroll
        for (int j = 0; j < 16; ++j) {
            const float hsb = hs + 0.4f;
            const float x = zv[j] + 4.0f * hf - 7.0f * hsb * hsb;
            const float hfn = fast_tanh(x);
            const float eps = 0.9f + 0.9f * fast_sigmoid(10.0f * (hf - 0.5f));
            hs = hs + eps * (hf - hs);
            h_t[base + (size_t)(l0 + j) * MEM] = hfn;
            hf = hfn;
        }
        if (more) {
#pragma unroll
            for (int j = 0; j < 16; ++j) zv[j] = zn[j];
        }
    }
    hf_last[idx] = hf;
}

extern "C" void kernel_launch(void* const* d_in, const int* in_sizes, int n_in,
                              void* d_out, int out_size, void* d_ws, size_t ws_size,
                              hipStream_t stream) {
    const float* u    = (const float*)d_in[0];   // (128,512,512)
    const float* h0   = (const float*)d_in[1];   // (2,128,1024)
    const float* W_im = (const float*)d_in[2];   // (2048,512)
    const float* b_im = (const float*)d_in[3];   // (2048,)

    float* out = (float*)d_out;
    float* h_t = out;
    float* hf_last = out + (size_t)M_ * MEM;

    // ws layout (~273 MB):
    //   z   : M_*MEM fp32      = 268,435,456 B
    //   wh  : N_*K_  fp16      =   2,097,152 B
    //   wl  : N_*K_  fp16      =   2,097,152 B
    char* ws = (char*)d_ws;
    float* z           = (float*)ws;
    unsigned short* wh = (unsigned short*)(ws + 268435456ull);
    unsigned short* wl = (unsigned short*)(ws + 270532608ull);

    // 1) split W fp32 -> fp16 hi/lo (scaled)
    {
        const int n4_w = (N_ * K_) / 4;
        split_fp32_fp16x2<<<(n4_w + 255) / 256, 256, 0, stream>>>(W_im, wh, wl, n4_w, SCALE_W);
    }
    // 2) paired GEMM (fp32-A on-the-fly split, 2-phase dbuf) -> fused z
    {
        gemm_paired_kernel<<<2048, 512, 0, stream>>>(u, wh, wl, b_im, z);
    }
    // 3) recurrence scan + hf_last
    {
        scan_kernel<<<(B_ * MEM) / 256, 256, 0, stream>>>(z, h_t, h0, hf_last);
    }
}